// Round 12
// baseline (149.812 us; speedup 1.0000x reference)
//
#include <hip/hip_runtime.h>

// Problem constants: T=1024, B=256, H=20
#define T_N 1024
#define B_N 256
#define H_N 20
#define NW  8            // waves per block
#define NDW (NW - 1)     // dot waves
#define SIH 1096         // I-history row stride in HALVES (conflict-free layout, see R5)

typedef _Float16 h8_t __attribute__((ext_vector_type(8)));

#if __has_builtin(__builtin_amdgcn_fdot2)
#define DOT8(acc, mv, iv)                                                           \
    acc = __builtin_amdgcn_fdot2(__builtin_shufflevector(mv, mv, 0, 1),             \
                                 __builtin_shufflevector(iv, iv, 0, 1), acc, false);\
    acc = __builtin_amdgcn_fdot2(__builtin_shufflevector(mv, mv, 2, 3),             \
                                 __builtin_shufflevector(iv, iv, 2, 3), acc, false);\
    acc = __builtin_amdgcn_fdot2(__builtin_shufflevector(mv, mv, 4, 5),             \
                                 __builtin_shufflevector(iv, iv, 4, 5), acc, false);\
    acc = __builtin_amdgcn_fdot2(__builtin_shufflevector(mv, mv, 6, 7),             \
                                 __builtin_shufflevector(iv, iv, 6, 7), acc, false);
#else
#define DOT8(acc, mv, iv)                                                           \
    _Pragma("unroll")                                                               \
    for (int _k = 0; _k < 8; ++_k) acc = fmaf((float)mv[_k], (float)iv[_k], acc);
#endif

__device__ __forceinline__ float rdlane_i(float v, int lane) {
    return __uint_as_float((unsigned)__builtin_amdgcn_readlane((int)__float_as_uint(v), lane));
}
__device__ __forceinline__ float fast_tanh(float x) {
    const float e = __expf(2.0f * x);
    return fmaf(-2.0f, __builtin_amdgcn_rcpf(e + 1.0f), 1.0f);
}
__device__ __forceinline__ float fast_sigmoid(float x) {
    return __builtin_amdgcn_rcpf(1.0f + __expf(-x));
}

// ---------------------------------------------------------------------------
// R12: LOOP-IFIED CHAIN (code-size attack). Evidence: R10 rep-scaling shows
// steady-state chunk loop = ~25us but single-shot = ~40us -> ~15us first-pass
// fixed cost; the only per-block once-only cost of that order is COLD
// INSTRUCTION FETCH of the ~20KB unrolled body (~300 lines x ~150cy from
// L2). Retrodiction: R3 (code x2 -> +11us) and R7 (code x1.5 -> +17us)
// regressions track code size, not op count. Fix: replace the 128 named
// register tables + 64-way macro unroll with ONE dt2-scaled LDS table
//   meS2[i] = dt2*me[i]  (i < 1024),  meS2[1024..1087] = 0
// Step M lane L:  rm = meS2[1024-L+M]  (pad auto-zeroes M >= L)
//                 rn = meS2[ 960-L+M]
// Both ds_read_b32 are lane-consecutive (conflict-free) and feed only the
// acc folds (OFF the S/I critical recurrence). The 64-step chain becomes a
// runtime loop (~2KB hot code); unified first-step via ms-multiplier
// (ms=0 first executed step, meT1s after). Identical arithmetic and order.
// Config = R6 (8 waves, PA/PB merge, setprio(3), me_kernel split).
// ---------------------------------------------------------------------------
__global__ __launch_bounds__(512, 1) void me_kernel(
    const float* __restrict__ t,
    const float* __restrict__ w1, const float* __restrict__ b1,
    const float* __restrict__ w2, const float* __restrict__ b2,
    const float* __restrict__ w3, const float* __restrict__ b3,
    const float* __restrict__ w4, const float* __restrict__ b4,
    float* __restrict__ me_f,        // [1024] fp32
    _Float16* __restrict__ me_h)     // [1024] fp16
{
    const int gid = blockIdx.x * 512 + threadIdx.x;   // 2 blocks x 512 = 1024
    const float x = t[gid];

    float h1[H_N], h2[H_N];
#pragma unroll
    for (int k = 0; k < H_N; ++k) h1[k] = fast_tanh(fmaf(x, w1[k], b1[k]));

#pragma unroll 4
    for (int k = 0; k < H_N; ++k) {
        float a = b2[k];
#pragma unroll
        for (int j = 0; j < H_N; ++j) a = fmaf(h1[j], w2[j * H_N + k], a);
        h2[k] = fast_tanh(a);
    }

    float a4 = b4[0];
#pragma unroll 4
    for (int k = 0; k < H_N; ++k) {
        float a = b3[k];
#pragma unroll
        for (int j = 0; j < H_N; ++j) a = fmaf(h2[j], w3[j * H_N + k], a);
        a4 = fmaf(fast_tanh(a), w4[k], a4);
    }

    const float meval = fast_sigmoid(a4);
    me_f[gid] = meval;
    me_h[gid] = (_Float16)meval;
}

__global__ __launch_bounds__(512, 1) void scan_kernel(
    const float* __restrict__ me_f,
    const _Float16* __restrict__ me_h,
    const float* __restrict__ t,
    const float* __restrict__ y,
    const float* __restrict__ beta_p,
    const float* __restrict__ gamma_p,
    float* __restrict__ out)     // [solution (T*B*3) | diff (T*B*3)]
{
    __shared__ __align__(16) float    sMeF[T_N];      // fp32 me (fixup weights)
    __shared__ __align__(16) _Float16 sMeH[T_N];      // fp16 me (dot operand A)
    __shared__ __align__(16) _Float16 sIhR[8 * SIH];  // 8 shifted fp16 I-history rows
    __shared__ __align__(16) float    PA[2][64][4];   // dot partials, waves 1-4
    __shared__ __align__(16) float    PB[2][64][4];   // dot partials, waves 5-7 (+zero slot)
    __shared__ __align__(16) float    meS2[T_N + 64]; // dt2-scaled me + zero pad

    const int b   = blockIdx.x;
    const int tid = threadIdx.x;
    const int wid = tid >> 6;
    const int L   = tid & 63;

    // per-lane dot-geometry constants (chunk-invariant)
    const int f    = (-L) & 7;            // misalignment of lane L's me window
    const int R8   = L + f;               // L rounded up to multiple of 8
    const int row  = L & 7;               // I-history row for this lane
    const int iofs = row * SIH + (f ? 0 : 8);

    // zero the row front-pads (slots representing I[<0])
    if (tid < 64) sIhR[(tid >> 3) * SIH + (tid & 7)] = (_Float16)0.0f;
    // zero the unused PB slot 3 for both parities
    if (tid < 128) PB[tid >> 6][tid & 63][3] = 0.0f;

    const float dt  = t[0] - t[1];
    const float dt2 = dt * dt;

    // ---- stage me from global (computed by me_kernel) + scaled table ----
#pragma unroll
    for (int v = 0; v < 2; ++v) {
        const int mi = tid + v * 512;
        const float mv = me_f[mi];
        sMeF[mi]  = mv;
        sMeH[mi]  = me_h[mi];
        meS2[mi]  = dt2 * mv;
    }
    if (tid < 64) meS2[T_N + tid] = 0.0f;   // pad: rm auto-zero for M >= L

    // ---- scalars / state ----
    const float beta  = beta_p[0];
    const float gma   = gamma_p[0];
    const float invdt = 1.0f / dt;

    const float S0 = y[b * 3 + 0];
    const float I0 = y[b * 3 + 1];
    const float R0 = y[b * 3 + 2];
    const float TOT = S0 + I0 + R0;     // SIR total conserved

    // publish I[0] into all 8 rows
    if (tid < 8) sIhR[tid * SIH + 8 - tid] = (_Float16)I0;

    float* __restrict__ diff = out + (size_t)T_N * B_N * 3;
    if (tid < 3) diff[((size_t)(T_N - 1) * B_N + b) * 3 + tid] = 0.0f;

    __syncthreads();   // sMeF/sMeH/meS2/pads/I0/PB-slot3 visible

    // fixup me weights (chunk-invariant, UNSCALED — applied to raw P sums)
    float mf[7];
#pragma unroll
    for (int d = 1; d <= 7; ++d) mf[d - 1] = sMeF[T_N - 64 - L - d];

    const float dtb   = dt * beta;
    const float ndtb  = -dtb;
    const float c1    = fmaf(-dt, gma, 1.0f);     // 1 - dt*gamma
    const float meT1s = meS2[T_N - 1];            // dt^2 * me[T-1]

    float S = S0, I = I0, oS = S0, oI = I0;
    float acc_cur = 0.0f, acc_nxt = 0.0f, pre = 0.0f;
    float carryS = S0, carryI = I0;

    const int TiL   = T_N - L;        // rm index base (step M reads TiL + M)
    const int TiL64 = T_N - 64 - L;   // rn index base

    if (wid == 0) {
        // wave0 priority: serial VALU wave vs 7 LDS-heavy dot waves (T5)
        __builtin_amdgcn_s_setprio(3);
    }

    for (int c = 0; c < 16; ++c) {
        if (wid == 0) {
            int Mstart;
            if (c == 0) {
                // fold initial I0 (tau=0 term); meS2 pad zeroes lane 0's rm
                acc_cur = meS2[TiL] * I;
                acc_nxt = meS2[TiL64] * I;
                pre = rdlane_i(acc_cur, 1);
                Mstart = 1;
            } else {
                // chunk-head merge: 2x consecutive-per-lane ds_read_b128
                const float4 pa = *(const float4*)&PA[c & 1][L][0];
                const float4 pb = *(const float4*)&PB[c & 1][L][0];
                const float ps = ((pa.x + pa.y) + (pa.z + pa.w)) +
                                 ((pb.x + pb.y) + (pb.z + pb.w));   // PB slot3 = 0
                acc_cur = fmaf(dt2, ps, acc_nxt);  // scale raw P sums
                acc_nxt = 0.0f;
                pre = rdlane_i(acc_cur, 0);
                Mstart = 0;
            }

            // serial chain, runtime loop (hot code ~2KB instead of ~20KB).
            // ms = 0 on the first executed step (sum = pre), meT1s after.
            float ms = 0.0f;
#pragma unroll 4
            for (int M = Mstart; M < 64; ++M) {
                const float rmv = meS2[TiL + M];      // off critical path
                const float rnv = meS2[TiL64 + M];    // off critical path
                const float sum = fmaf(ms, I, pre);
                ms = meT1s;
                const float pnx = rdlane_i(acc_cur, (M + 1) & 63); // M=63: dead
                const float a  = fmaf(dtb, S, c1);
                const float bb = fmaf(ndtb, I, 1.0f);
                S = fmaf(bb, S, sum);
                I = I * a;
                const bool cap = (L == M);
                oS = cap ? S : oS;
                oI = cap ? I : oI;
                acc_cur = fmaf(rmv, I, acc_cur);
                acc_nxt = fmaf(rnv, I, acc_nxt);
                pre = pnx;
            }

            // ---- chunk epilogue (wave 0) ----
            const int j = 64 * c + L;
            const _Float16 hI = (_Float16)oI;
#pragma unroll
            for (int r = 0; r < 8; ++r) sIhR[r * SIH + 8 + (j - r)] = hI;

            const float oR = TOT - oS - oI;
            const size_t so = ((size_t)j * B_N + b) * 3;
            out[so + 0] = oS;
            out[so + 1] = oI;
            out[so + 2] = oR;

            float sm1 = __shfl_up(oS, 1);
            float im1 = __shfl_up(oI, 1);
            if (L == 0) { sm1 = carryS; im1 = carryI; }
            if (j > 0) {
                const float d0 = (oS - sm1) * invdt;
                const float d1 = (oI - im1) * invdt;
                const float d2 = -d0 - d1;
                const size_t dofs = ((size_t)(j - 1) * B_N + b) * 3;
                diff[dofs + 0] = d0;
                diff[dofs + 1] = d1;
                diff[dofs + 2] = d2;
            }
            carryS = rdlane_i(oS, 63);
            carryI = rdlane_i(oI, 63);
        } else if (c < 15) {
            // history dot for chunk c+1 over tau < 64c (R5 layout, unchanged)
            const int w    = wid - 1;
            const int G    = 8 * c;
            const int idx0 = (T_N - 64 * (c + 1)) - R8;
            float p0 = 0.0f, p1 = 0.0f;
            int s = w;
            for (; s + NDW < G; s += 2 * NDW) {
                const h8_t mv0 = *(const h8_t*)&sMeH[idx0 + 8 * s];
                const h8_t iv0 = *(const h8_t*)&sIhR[iofs + 8 * s];
                const h8_t mv1 = *(const h8_t*)&sMeH[idx0 + 8 * (s + NDW)];
                const h8_t iv1 = *(const h8_t*)&sIhR[iofs + 8 * (s + NDW)];
                DOT8(p0, mv0, iv0)
                DOT8(p1, mv1, iv1)
            }
            if (s < G) {
                const h8_t mv0 = *(const h8_t*)&sMeH[idx0 + 8 * s];
                const h8_t iv0 = *(const h8_t*)&sIhR[iofs + 8 * s];
                DOT8(p0, mv0, iv0)
            }
            float p = p0 + p1;
            if (w == 0) {
                // tail fixup: tau = 64c - d, d = 1..f (raw, scaled at merge)
#pragma unroll
                for (int d = 1; d <= 7; ++d) {
                    const float ih = (float)sIhR[8 + 64 * c - d];   // row 0
                    if (d <= f) p = fmaf(mf[d - 1], ih, p);
                }
            }
            if (w < 4) PA[(c + 1) & 1][L][w] = p;
            else       PB[(c + 1) & 1][L][w - 4] = p;
        }
        __syncthreads();
    }
}

// ---------------------------------------------------------------------------
// Launcher: me_kernel (2 blocks) then scan_kernel (256 blocks x 512 threads).
// d_ws layout: [0,4096) fp32 me; [4096,6144) fp16 me.
// ---------------------------------------------------------------------------
extern "C" void kernel_launch(void* const* d_in, const int* in_sizes, int n_in,
                              void* d_out, int out_size, void* d_ws, size_t ws_size,
                              hipStream_t stream) {
    const float* t     = (const float*)d_in[0];
    const float* y     = (const float*)d_in[1];
    const float* w1    = (const float*)d_in[2];
    const float* b1    = (const float*)d_in[3];
    const float* w2    = (const float*)d_in[4];
    const float* b2    = (const float*)d_in[5];
    const float* w3    = (const float*)d_in[6];
    const float* b3    = (const float*)d_in[7];
    const float* w4    = (const float*)d_in[8];
    const float* b4    = (const float*)d_in[9];
    const float* beta  = (const float*)d_in[10];
    const float* gamma = (const float*)d_in[11];

    float*    me_f = (float*)d_ws;
    _Float16* me_h = (_Float16*)((char*)d_ws + 4096);

    me_kernel<<<2, 512, 0, stream>>>(t, w1, b1, w2, b2, w3, b3, w4, b4, me_f, me_h);
    scan_kernel<<<B_N, 512, 0, stream>>>(me_f, me_h, t, y, beta, gamma, (float*)d_out);
}

// Round 13
// 113.980 us; speedup vs baseline: 1.3144x; 1.3144x over previous
//
#include <hip/hip_runtime.h>

// Problem constants: T=1024, B=256, H=20
#define T_N 1024
#define B_N 256
#define H_N 20
#define NW  8            // waves per block (wave 4 intentionally IDLE, see R13)
#define NDW 6            // active dot waves: wid 1,2,3,5,6,7
#define SIH 1096         // I-history row stride in HALVES (conflict-free layout, see R5)

typedef _Float16 h8_t __attribute__((ext_vector_type(8)));

#if __has_builtin(__builtin_amdgcn_fdot2)
#define DOT8(acc, mv, iv)                                                           \
    acc = __builtin_amdgcn_fdot2(__builtin_shufflevector(mv, mv, 0, 1),             \
                                 __builtin_shufflevector(iv, iv, 0, 1), acc, false);\
    acc = __builtin_amdgcn_fdot2(__builtin_shufflevector(mv, mv, 2, 3),             \
                                 __builtin_shufflevector(iv, iv, 2, 3), acc, false);\
    acc = __builtin_amdgcn_fdot2(__builtin_shufflevector(mv, mv, 4, 5),             \
                                 __builtin_shufflevector(iv, iv, 4, 5), acc, false);\
    acc = __builtin_amdgcn_fdot2(__builtin_shufflevector(mv, mv, 6, 7),             \
                                 __builtin_shufflevector(iv, iv, 6, 7), acc, false);
#else
#define DOT8(acc, mv, iv)                                                           \
    _Pragma("unroll")                                                               \
    for (int _k = 0; _k < 8; ++_k) acc = fmaf((float)mv[_k], (float)iv[_k], acc);
#endif

__device__ __forceinline__ float rdlane_i(float v, int lane) {
    return __uint_as_float((unsigned)__builtin_amdgcn_readlane((int)__float_as_uint(v), lane));
}
__device__ __forceinline__ float fast_tanh(float x) {
    const float e = __expf(2.0f * x);
    return fmaf(-2.0f, __builtin_amdgcn_rcpf(e + 1.0f), 1.0f);
}
__device__ __forceinline__ float fast_sigmoid(float x) {
    return __builtin_amdgcn_rcpf(1.0f + __expf(-x));
}

// explicit literal-token repetition (tokens must be plain literals for ##)
#define REP64(F) \
    F(0) F(1) F(2) F(3) F(4) F(5) F(6) F(7) F(8) F(9) F(10) F(11) F(12) F(13) \
    F(14) F(15) F(16) F(17) F(18) F(19) F(20) F(21) F(22) F(23) F(24) F(25)   \
    F(26) F(27) F(28) F(29) F(30) F(31) F(32) F(33) F(34) F(35) F(36) F(37)   \
    F(38) F(39) F(40) F(41) F(42) F(43) F(44) F(45) F(46) F(47) F(48) F(49)   \
    F(50) F(51) F(52) F(53) F(54) F(55) F(56) F(57) F(58) F(59) F(60) F(61)   \
    F(62) F(63)

// ---------------------------------------------------------------------------
// R13: PRIVATE SIMD FOR WAVE 0, DOTS KEPT FED. Evidence chain:
//  - R10 rep-scaling: steady-state chain ~25us (60cy/step) vs static model
//    ~30cy/step -> ~2x inflation proportional to op count.
//  - R11 (4 waves): wave0 private SIMD but only 3 dot waves -> dots went
//    critical, +12us. Theory not falsified, just starved.
//  - R12 (loop-ify): LDS reads on the serial path, -30us. Reverted.
// The 2x signature matches round-robin SIMD issue arbitration: wave 4
// co-resides on wave0's SIMD (i%4 mapping) and its fdot2 stream steals
// ~half the issue slots (setprio barely helps, R5/m190).
// Fix: 8-wave block, wave 4 IDLE (parks at s_barrier, issues nothing) ->
// SIMD0 private to wave0; 6 dot waves on SIMDs 1-3 (two each). Worst-chunk
// dot load: 112 segs / 6 waves ~= 600cy << chain ~2kcy -> dots stay hidden.
// Base otherwise identical to R6 (best, 114.2us): me_kernel split, register
// me-tables + full unroll, PA/PB conflict-free merge, distance-1 readlane,
// setprio(3), dt^2-folded algebra.
// ---------------------------------------------------------------------------
__global__ __launch_bounds__(512, 1) void me_kernel(
    const float* __restrict__ t,
    const float* __restrict__ w1, const float* __restrict__ b1,
    const float* __restrict__ w2, const float* __restrict__ b2,
    const float* __restrict__ w3, const float* __restrict__ b3,
    const float* __restrict__ w4, const float* __restrict__ b4,
    float* __restrict__ me_f,        // [1024] fp32
    _Float16* __restrict__ me_h)     // [1024] fp16
{
    const int gid = blockIdx.x * 512 + threadIdx.x;   // 2 blocks x 512 = 1024
    const float x = t[gid];

    float h1[H_N], h2[H_N];
#pragma unroll
    for (int k = 0; k < H_N; ++k) h1[k] = fast_tanh(fmaf(x, w1[k], b1[k]));

#pragma unroll 4
    for (int k = 0; k < H_N; ++k) {
        float a = b2[k];
#pragma unroll
        for (int j = 0; j < H_N; ++j) a = fmaf(h1[j], w2[j * H_N + k], a);
        h2[k] = fast_tanh(a);
    }

    float a4 = b4[0];
#pragma unroll 4
    for (int k = 0; k < H_N; ++k) {
        float a = b3[k];
#pragma unroll
        for (int j = 0; j < H_N; ++j) a = fmaf(h2[j], w3[j * H_N + k], a);
        a4 = fmaf(fast_tanh(a), w4[k], a4);
    }

    const float meval = fast_sigmoid(a4);
    me_f[gid] = meval;
    me_h[gid] = (_Float16)meval;
}

__global__ __launch_bounds__(512, 1) void scan_kernel(
    const float* __restrict__ me_f,
    const _Float16* __restrict__ me_h,
    const float* __restrict__ t,
    const float* __restrict__ y,
    const float* __restrict__ beta_p,
    const float* __restrict__ gamma_p,
    float* __restrict__ out)     // [solution (T*B*3) | diff (T*B*3)]
{
    __shared__ __align__(16) float    sMeF[T_N];      // fp32 me
    __shared__ __align__(16) _Float16 sMeH[T_N];      // fp16 me (dot operand A)
    __shared__ __align__(16) _Float16 sIhR[8 * SIH];  // 8 shifted fp16 I-history rows
    __shared__ __align__(16) float    PA[2][64][4];   // dot partials, w 0-3
    __shared__ __align__(16) float    PB[2][64][4];   // dot partials, w 4-5 (+2 zero slots)

    const int b   = blockIdx.x;
    const int tid = threadIdx.x;
    const int wid = tid >> 6;
    const int L   = tid & 63;

    // per-lane dot-geometry constants (chunk-invariant)
    const int f    = (-L) & 7;            // misalignment of lane L's me window
    const int R8   = L + f;               // L rounded up to multiple of 8
    const int row  = L & 7;               // I-history row for this lane
    const int iofs = row * SIH + (f ? 0 : 8);

    // zero the row front-pads (slots representing I[<0])
    if (tid < 64) sIhR[(tid >> 3) * SIH + (tid & 7)] = (_Float16)0.0f;
    // zero PB slots 2 and 3 for both parities (only w=4,5 write PB)
    if (tid < 256) PB[(tid >> 6) & 1][tid & 63][2 + (tid >> 7)] = 0.0f;

    // ---- stage me from global (computed by me_kernel) ----
#pragma unroll
    for (int v = 0; v < 2; ++v) {
        const int mi = tid + v * 512;
        sMeF[mi] = me_f[mi];
        sMeH[mi] = me_h[mi];
    }

    // ---- scalars / state ----
    const float dt    = t[0] - t[1];
    const float beta  = beta_p[0];
    const float gma   = gamma_p[0];
    const float invdt = 1.0f / dt;
    const float dt2   = dt * dt;

    const float S0 = y[b * 3 + 0];
    const float I0 = y[b * 3 + 1];
    const float R0 = y[b * 3 + 2];
    const float TOT = S0 + I0 + R0;     // SIR total conserved

    // publish I[0] into all 8 rows
    if (tid < 8) sIhR[tid * SIH + 8 - tid] = (_Float16)I0;

    float* __restrict__ diff = out + (size_t)T_N * B_N * 3;
    if (tid < 3) diff[((size_t)(T_N - 1) * B_N + b) * 3 + tid] = 0.0f;

    __syncthreads();   // sMeF/sMeH/pads/I0/PB-zeros visible

    // fixup me weights (chunk-invariant, UNSCALED — applied to raw P sums)
    float mf[7];
#pragma unroll
    for (int d = 1; d <= 7; ++d) mf[d - 1] = sMeF[T_N - 64 - L - d];

    const float dtb   = dt * beta;
    const float ndtb  = -dtb;
    const float c1    = fmaf(-dt, gma, 1.0f);     // 1 - dt*gamma
    const float meT1s = dt2 * sMeF[T_N - 1];      // dt^2 * me[T-1]

    float S = S0, I = I0, oS = S0, oI = I0;
    float acc_cur = 0.0f, acc_nxt = 0.0f, pre = 0.0f;
    float carryS = S0, carryI = I0;

    // register me-tables (dt^2-scaled): 128 NAMED scalars
#define TBLDECL(k) float rm_##k, rn_##k;
    REP64(TBLDECL)
#undef TBLDECL
    if (wid == 0) {
#define TBLINIT(k)                                                          \
        rm_##k = (((k) < L) ? sMeF[T_N - L + (k)] : 0.0f) * dt2;            \
        rn_##k = dt2 * sMeF[T_N - 64 - L + (k)];
        REP64(TBLINIT)
#undef TBLINIT
#define TBLPIN(k) asm volatile("" : "+v"(rm_##k), "+v"(rn_##k));
        REP64(TBLPIN)
#undef TBLPIN
        __builtin_amdgcn_s_setprio(3);
    }

    // serial step M_: entering (S,I) = y_{64c+M_-1}; produces y_{64c+M_}.
    // pre was read BEFORE step (M_-1)'s fold -> patch with meT1s*I.
#define STEPB(M_, FIRST_)                                               \
    {                                                                   \
        const float sum = (FIRST_) ? pre : fmaf(meT1s, I, pre);         \
        float pnx = pre;                                                \
        if ((M_) < 63) pnx = rdlane_i(acc_cur, (M_) + 1);               \
        const float a  = fmaf(dtb, S, c1);                              \
        const float bb = fmaf(ndtb, I, 1.0f);                           \
        S = fmaf(bb, S, sum);                                           \
        I = I * a;                                                      \
        const bool cap = (L == (M_));                                   \
        oS = cap ? S : oS;                                              \
        oI = cap ? I : oI;                                              \
        acc_cur = fmaf(rm_##M_, I, acc_cur);                            \
        acc_nxt = fmaf(rn_##M_, I, acc_nxt);                            \
        pre = pnx;                                                      \
    }
#define STEP_GE1(M_) if ((M_) >= 1) STEPB(M_, false)
#define STEP_GE2(M_) if ((M_) >= 2) STEPB(M_, false)

    for (int c = 0; c < 16; ++c) {
        if (wid == 0) {
            if (c == 0) {
                // fold initial I0 (tau=0 term); lane0's rm_0 is the 0 pad
                acc_cur = rm_0 * I;
                acc_nxt = rn_0 * I;
                pre = rdlane_i(acc_cur, 1);
                STEPB(1, true)
                REP64(STEP_GE2)
            } else {
                // chunk-head merge: 2x consecutive-per-lane ds_read_b128
                const float4 pa = *(const float4*)&PA[c & 1][L][0];
                const float4 pb = *(const float4*)&PB[c & 1][L][0];
                const float ps = ((pa.x + pa.y) + (pa.z + pa.w)) +
                                 ((pb.x + pb.y) + (pb.z + pb.w));   // PB 2,3 = 0
                acc_cur = fmaf(dt2, ps, acc_nxt);  // scale raw P sums
                acc_nxt = 0.0f;
                pre = rdlane_i(acc_cur, 0);
                STEPB(0, true)
                REP64(STEP_GE1)
            }

            // ---- chunk epilogue (wave 0) ----
            const int j = 64 * c + L;
            const _Float16 hI = (_Float16)oI;
#pragma unroll
            for (int r = 0; r < 8; ++r) sIhR[r * SIH + 8 + (j - r)] = hI;

            const float oR = TOT - oS - oI;
            const size_t so = ((size_t)j * B_N + b) * 3;
            out[so + 0] = oS;
            out[so + 1] = oI;
            out[so + 2] = oR;

            float sm1 = __shfl_up(oS, 1);
            float im1 = __shfl_up(oI, 1);
            if (L == 0) { sm1 = carryS; im1 = carryI; }
            if (j > 0) {
                const float d0 = (oS - sm1) * invdt;
                const float d1 = (oI - im1) * invdt;
                const float d2 = -d0 - d1;
                const size_t dofs = ((size_t)(j - 1) * B_N + b) * 3;
                diff[dofs + 0] = d0;
                diff[dofs + 1] = d1;
                diff[dofs + 2] = d2;
            }
            carryS = rdlane_i(oS, 63);
            carryI = rdlane_i(oI, 63);
        } else if (c < 15 && wid != 4) {
            // R13: wave 4 shares wave0's SIMD (round-robin i%4) -> kept IDLE.
            // Active dot waves: wid 1,2,3 -> w 0,1,2 ; wid 5,6,7 -> w 3,4,5.
            const int w    = (wid < 4) ? (wid - 1) : (wid - 2);
            const int G    = 8 * c;
            const int idx0 = (T_N - 64 * (c + 1)) - R8;
            float p0 = 0.0f, p1 = 0.0f;
            int s = w;
            for (; s + NDW < G; s += 2 * NDW) {
                const h8_t mv0 = *(const h8_t*)&sMeH[idx0 + 8 * s];
                const h8_t iv0 = *(const h8_t*)&sIhR[iofs + 8 * s];
                const h8_t mv1 = *(const h8_t*)&sMeH[idx0 + 8 * (s + NDW)];
                const h8_t iv1 = *(const h8_t*)&sIhR[iofs + 8 * (s + NDW)];
                DOT8(p0, mv0, iv0)
                DOT8(p1, mv1, iv1)
            }
            if (s < G) {
                const h8_t mv0 = *(const h8_t*)&sMeH[idx0 + 8 * s];
                const h8_t iv0 = *(const h8_t*)&sIhR[iofs + 8 * s];
                DOT8(p0, mv0, iv0)
            }
            float p = p0 + p1;
            if (w == 0) {
                // tail fixup: tau = 64c - d, d = 1..f (raw, scaled at merge)
#pragma unroll
                for (int d = 1; d <= 7; ++d) {
                    const float ih = (float)sIhR[8 + 64 * c - d];   // row 0
                    if (d <= f) p = fmaf(mf[d - 1], ih, p);
                }
            }
            if (w < 4) PA[(c + 1) & 1][L][w] = p;
            else       PB[(c + 1) & 1][L][w - 4] = p;
        }
        __syncthreads();
    }
#undef STEPB
#undef STEP_GE1
#undef STEP_GE2
}

// ---------------------------------------------------------------------------
// Launcher: me_kernel (2 blocks) then scan_kernel (256 blocks x 512 threads).
// d_ws layout: [0,4096) fp32 me; [4096,6144) fp16 me.
// ---------------------------------------------------------------------------
extern "C" void kernel_launch(void* const* d_in, const int* in_sizes, int n_in,
                              void* d_out, int out_size, void* d_ws, size_t ws_size,
                              hipStream_t stream) {
    const float* t     = (const float*)d_in[0];
    const float* y     = (const float*)d_in[1];
    const float* w1    = (const float*)d_in[2];
    const float* b1    = (const float*)d_in[3];
    const float* w2    = (const float*)d_in[4];
    const float* b2    = (const float*)d_in[5];
    const float* w3    = (const float*)d_in[6];
    const float* b3    = (const float*)d_in[7];
    const float* w4    = (const float*)d_in[8];
    const float* b4    = (const float*)d_in[9];
    const float* beta  = (const float*)d_in[10];
    const float* gamma = (const float*)d_in[11];

    float*    me_f = (float*)d_ws;
    _Float16* me_h = (_Float16*)((char*)d_ws + 4096);

    me_kernel<<<2, 512, 0, stream>>>(t, w1, b1, w2, b2, w3, b3, w4, b4, me_f, me_h);
    scan_kernel<<<B_N, 512, 0, stream>>>(me_f, me_h, t, y, beta, gamma, (float*)d_out);
}

// Round 14
// 111.454 us; speedup vs baseline: 1.3442x; 1.0227x over previous
//
#include <hip/hip_runtime.h>

// Problem constants: T=1024, B=256, H=20
#define T_N 1024
#define B_N 256
#define H_N 20
#define NW  8            // waves per block (wave 4 intentionally IDLE, see R13)
#define NDW 6            // active dot waves: wid 1,2,3,5,6,7
#define SIH 1096         // I-history row stride in HALVES (conflict-free layout, see R5)

typedef _Float16 h8_t __attribute__((ext_vector_type(8)));
typedef float    f2   __attribute__((ext_vector_type(2)));

#if __has_builtin(__builtin_amdgcn_fdot2)
#define DOT8(acc, mv, iv)                                                           \
    acc = __builtin_amdgcn_fdot2(__builtin_shufflevector(mv, mv, 0, 1),             \
                                 __builtin_shufflevector(iv, iv, 0, 1), acc, false);\
    acc = __builtin_amdgcn_fdot2(__builtin_shufflevector(mv, mv, 2, 3),             \
                                 __builtin_shufflevector(iv, iv, 2, 3), acc, false);\
    acc = __builtin_amdgcn_fdot2(__builtin_shufflevector(mv, mv, 4, 5),             \
                                 __builtin_shufflevector(iv, iv, 4, 5), acc, false);\
    acc = __builtin_amdgcn_fdot2(__builtin_shufflevector(mv, mv, 6, 7),             \
                                 __builtin_shufflevector(iv, iv, 6, 7), acc, false);
#else
#define DOT8(acc, mv, iv)                                                           \
    _Pragma("unroll")                                                               \
    for (int _k = 0; _k < 8; ++_k) acc = fmaf((float)mv[_k], (float)iv[_k], acc);
#endif

__device__ __forceinline__ float rdlane_i(float v, int lane) {
    return __uint_as_float((unsigned)__builtin_amdgcn_readlane((int)__float_as_uint(v), lane));
}
__device__ __forceinline__ float fast_tanh(float x) {
    const float e = __expf(2.0f * x);
    return fmaf(-2.0f, __builtin_amdgcn_rcpf(e + 1.0f), 1.0f);
}
__device__ __forceinline__ float fast_sigmoid(float x) {
    return __builtin_amdgcn_rcpf(1.0f + __expf(-x));
}

// explicit literal-token repetition (tokens must be plain literals for ##)
#define REP64(F) \
    F(0) F(1) F(2) F(3) F(4) F(5) F(6) F(7) F(8) F(9) F(10) F(11) F(12) F(13) \
    F(14) F(15) F(16) F(17) F(18) F(19) F(20) F(21) F(22) F(23) F(24) F(25)   \
    F(26) F(27) F(28) F(29) F(30) F(31) F(32) F(33) F(34) F(35) F(36) F(37)   \
    F(38) F(39) F(40) F(41) F(42) F(43) F(44) F(45) F(46) F(47) F(48) F(49)   \
    F(50) F(51) F(52) F(53) F(54) F(55) F(56) F(57) F(58) F(59) F(60) F(61)   \
    F(62) F(63)

// ---------------------------------------------------------------------------
// R14: PACKED FP32 STEP (v_pk_fma_f32, VOP3P) — the one untested mechanism
// class after 8 refuted step-serializer theories (store-drain R1, remat R2,
// readlane distance R4, cadence R7, vcc R9, arbitration R11/R13, loop-ify
// R12). Three step pairs fuse into one packed fma each:
//   AB  = (dtb,ndtb)*(S,I) + (c1,1)          // (a,bb), default op_sel
//   SI' = (bb,a)*(S,I) + (sum,0)             // op_sel:[1,0,0] op_sel_hi:[0,1,1]
//   ACC+= (rm,rn)*I                          // op_sel:[0,1,0] (broadcast SI.hi)
// 11 -> 8 instr/step; identical fma operations in identical order -> absmax
// must stay 0.0078125 exactly (correctness check on the op_sel encoding).
// Dep cycle unchanged (SI -> AB -> SI', 2 chained fmas). Tables = 64 f2
// pairs (same 128 VGPRs). Base = R13 (me-split, wave4 idle, 6 dot waves,
// PA/PB merge, setprio(3)).
// ---------------------------------------------------------------------------
__global__ __launch_bounds__(512, 1) void me_kernel(
    const float* __restrict__ t,
    const float* __restrict__ w1, const float* __restrict__ b1,
    const float* __restrict__ w2, const float* __restrict__ b2,
    const float* __restrict__ w3, const float* __restrict__ b3,
    const float* __restrict__ w4, const float* __restrict__ b4,
    float* __restrict__ me_f,        // [1024] fp32
    _Float16* __restrict__ me_h)     // [1024] fp16
{
    const int gid = blockIdx.x * 512 + threadIdx.x;   // 2 blocks x 512 = 1024
    const float x = t[gid];

    float h1[H_N], h2[H_N];
#pragma unroll
    for (int k = 0; k < H_N; ++k) h1[k] = fast_tanh(fmaf(x, w1[k], b1[k]));

#pragma unroll 4
    for (int k = 0; k < H_N; ++k) {
        float a = b2[k];
#pragma unroll
        for (int j = 0; j < H_N; ++j) a = fmaf(h1[j], w2[j * H_N + k], a);
        h2[k] = fast_tanh(a);
    }

    float a4 = b4[0];
#pragma unroll 4
    for (int k = 0; k < H_N; ++k) {
        float a = b3[k];
#pragma unroll
        for (int j = 0; j < H_N; ++j) a = fmaf(h2[j], w3[j * H_N + k], a);
        a4 = fmaf(fast_tanh(a), w4[k], a4);
    }

    const float meval = fast_sigmoid(a4);
    me_f[gid] = meval;
    me_h[gid] = (_Float16)meval;
}

__global__ __launch_bounds__(512, 1) void scan_kernel(
    const float* __restrict__ me_f,
    const _Float16* __restrict__ me_h,
    const float* __restrict__ t,
    const float* __restrict__ y,
    const float* __restrict__ beta_p,
    const float* __restrict__ gamma_p,
    float* __restrict__ out)     // [solution (T*B*3) | diff (T*B*3)]
{
    __shared__ __align__(16) float    sMeF[T_N];      // fp32 me
    __shared__ __align__(16) _Float16 sMeH[T_N];      // fp16 me (dot operand A)
    __shared__ __align__(16) _Float16 sIhR[8 * SIH];  // 8 shifted fp16 I-history rows
    __shared__ __align__(16) float    PA[2][64][4];   // dot partials, w 0-3
    __shared__ __align__(16) float    PB[2][64][4];   // dot partials, w 4-5 (+2 zero slots)

    const int b   = blockIdx.x;
    const int tid = threadIdx.x;
    const int wid = tid >> 6;
    const int L   = tid & 63;

    // per-lane dot-geometry constants (chunk-invariant)
    const int f    = (-L) & 7;            // misalignment of lane L's me window
    const int R8   = L + f;               // L rounded up to multiple of 8
    const int row  = L & 7;               // I-history row for this lane
    const int iofs = row * SIH + (f ? 0 : 8);

    // zero the row front-pads (slots representing I[<0])
    if (tid < 64) sIhR[(tid >> 3) * SIH + (tid & 7)] = (_Float16)0.0f;
    // zero PB slots 2 and 3 for both parities (only w=4,5 write PB)
    if (tid < 256) PB[(tid >> 6) & 1][tid & 63][2 + (tid >> 7)] = 0.0f;

    // ---- stage me from global (computed by me_kernel) ----
#pragma unroll
    for (int v = 0; v < 2; ++v) {
        const int mi = tid + v * 512;
        sMeF[mi] = me_f[mi];
        sMeH[mi] = me_h[mi];
    }

    // ---- scalars / state ----
    const float dt    = t[0] - t[1];
    const float beta  = beta_p[0];
    const float gma   = gamma_p[0];
    const float invdt = 1.0f / dt;
    const float dt2   = dt * dt;

    const float S0 = y[b * 3 + 0];
    const float I0 = y[b * 3 + 1];
    const float R0 = y[b * 3 + 2];
    const float TOT = S0 + I0 + R0;     // SIR total conserved

    // publish I[0] into all 8 rows
    if (tid < 8) sIhR[tid * SIH + 8 - tid] = (_Float16)I0;

    float* __restrict__ diff = out + (size_t)T_N * B_N * 3;
    if (tid < 3) diff[((size_t)(T_N - 1) * B_N + b) * 3 + tid] = 0.0f;

    __syncthreads();   // sMeF/sMeH/pads/I0/PB-zeros visible

    // fixup me weights (chunk-invariant, UNSCALED — applied to raw P sums)
    float mf[7];
#pragma unroll
    for (int d = 1; d <= 7; ++d) mf[d - 1] = sMeF[T_N - 64 - L - d];

    const float dtb   = dt * beta;
    const float ndtb  = -dtb;
    const float c1    = fmaf(-dt, gma, 1.0f);     // 1 - dt*gamma
    const float meT1s = dt2 * sMeF[T_N - 1];      // dt^2 * me[T-1]

    // packed constants / state
    f2 DTN;  DTN.x = dtb;  DTN.y = ndtb;          // (dtb, -dtb)
    f2 C1v;  C1v.x = c1;   C1v.y = 1.0f;          // (c1, 1)
    f2 SI;   SI.x  = S0;   SI.y  = I0;            // (S, I)
    f2 ACC;  ACC.x = 0.0f; ACC.y = 0.0f;          // (acc_cur, acc_nxt)
    f2 SUMv; SUMv.x = 0.0f; SUMv.y = 0.0f;        // (sum, 0) — .y stays 0
    float oS = S0, oI = I0, pre = 0.0f;
    float carryS = S0, carryI = I0;

    // register me-tables (dt^2-scaled), packed: 64 NAMED f2 pairs (128 VGPRs)
#define TBLDECL(k) f2 rp_##k;
    REP64(TBLDECL)
#undef TBLDECL
    if (wid == 0) {
#define TBLINIT(k)                                                          \
        rp_##k.x = (((k) < L) ? sMeF[T_N - L + (k)] : 0.0f) * dt2;          \
        rp_##k.y = dt2 * sMeF[T_N - 64 - L + (k)];
        REP64(TBLINIT)
#undef TBLINIT
#define TBLPIN(k) asm volatile("" : "+v"(rp_##k));
        REP64(TBLPIN)
#undef TBLPIN
        __builtin_amdgcn_s_setprio(3);
    }

    // serial step M_: entering SI = y_{64c+M_-1}; produces y_{64c+M_}.
    // pre was read BEFORE step (M_-1)'s fold -> patch with meT1s*I.
    // Packed ops (identical fma operations as scalar version, same order):
    //  AB  = DTN*SI + C1           -> (a, bb)
    //  SI  = (AB swapped)*SI + SUM -> (bb*S+sum, a*I+0)
    //  ACC = rp*broadcast(I) + ACC -> (acc_cur+rm*I, acc_nxt+rn*I)
#define STEPB(M_, FIRST_)                                               \
    {                                                                   \
        SUMv.x = (FIRST_) ? pre : fmaf(meT1s, SI.y, pre);               \
        float pnx = pre;                                                \
        if ((M_) < 63) pnx = rdlane_i(ACC.x, (M_) + 1);                 \
        f2 AB;                                                          \
        asm("v_pk_fma_f32 %0, %1, %2, %3"                               \
            : "=v"(AB) : "v"(DTN), "v"(SI), "v"(C1v));                  \
        asm("v_pk_fma_f32 %0, %1, %0, %2 op_sel:[1,0,0] op_sel_hi:[0,1,1]" \
            : "+v"(SI) : "v"(AB), "v"(SUMv));                           \
        const bool cap = (L == (M_));                                   \
        oS = cap ? SI.x : oS;                                           \
        oI = cap ? SI.y : oI;                                           \
        asm("v_pk_fma_f32 %0, %1, %2, %0 op_sel:[0,1,0] op_sel_hi:[1,1,1]" \
            : "+v"(ACC) : "v"(rp_##M_), "v"(SI));                       \
        pre = pnx;                                                      \
    }
#define STEP_GE1(M_) if ((M_) >= 1) STEPB(M_, false)
#define STEP_GE2(M_) if ((M_) >= 2) STEPB(M_, false)

    for (int c = 0; c < 16; ++c) {
        if (wid == 0) {
            if (c == 0) {
                // fold initial I0 (tau=0 term); lane0's rp_0.x is the 0 pad
                ACC.x = rp_0.x * SI.y;
                ACC.y = rp_0.y * SI.y;
                pre = rdlane_i(ACC.x, 1);
                STEPB(1, true)
                REP64(STEP_GE2)
            } else {
                // chunk-head merge: 2x consecutive-per-lane ds_read_b128
                const float4 pa = *(const float4*)&PA[c & 1][L][0];
                const float4 pb = *(const float4*)&PB[c & 1][L][0];
                const float ps = ((pa.x + pa.y) + (pa.z + pa.w)) +
                                 ((pb.x + pb.y) + (pb.z + pb.w));   // PB 2,3 = 0
                ACC.x = fmaf(dt2, ps, ACC.y);      // scale raw P sums + acc_nxt
                ACC.y = 0.0f;
                pre = rdlane_i(ACC.x, 0);
                STEPB(0, true)
                REP64(STEP_GE1)
            }

            // ---- chunk epilogue (wave 0) ----
            const int j = 64 * c + L;
            const _Float16 hI = (_Float16)oI;
#pragma unroll
            for (int r = 0; r < 8; ++r) sIhR[r * SIH + 8 + (j - r)] = hI;

            const float oR = TOT - oS - oI;
            const size_t so = ((size_t)j * B_N + b) * 3;
            out[so + 0] = oS;
            out[so + 1] = oI;
            out[so + 2] = oR;

            float sm1 = __shfl_up(oS, 1);
            float im1 = __shfl_up(oI, 1);
            if (L == 0) { sm1 = carryS; im1 = carryI; }
            if (j > 0) {
                const float d0 = (oS - sm1) * invdt;
                const float d1 = (oI - im1) * invdt;
                const float d2 = -d0 - d1;
                const size_t dofs = ((size_t)(j - 1) * B_N + b) * 3;
                diff[dofs + 0] = d0;
                diff[dofs + 1] = d1;
                diff[dofs + 2] = d2;
            }
            carryS = rdlane_i(oS, 63);
            carryI = rdlane_i(oI, 63);
        } else if (c < 15 && wid != 4) {
            // wave 4 shares wave0's SIMD (round-robin i%4) -> kept IDLE.
            // Active dot waves: wid 1,2,3 -> w 0,1,2 ; wid 5,6,7 -> w 3,4,5.
            const int w    = (wid < 4) ? (wid - 1) : (wid - 2);
            const int G    = 8 * c;
            const int idx0 = (T_N - 64 * (c + 1)) - R8;
            float p0 = 0.0f, p1 = 0.0f;
            int s = w;
            for (; s + NDW < G; s += 2 * NDW) {
                const h8_t mv0 = *(const h8_t*)&sMeH[idx0 + 8 * s];
                const h8_t iv0 = *(const h8_t*)&sIhR[iofs + 8 * s];
                const h8_t mv1 = *(const h8_t*)&sMeH[idx0 + 8 * (s + NDW)];
                const h8_t iv1 = *(const h8_t*)&sIhR[iofs + 8 * (s + NDW)];
                DOT8(p0, mv0, iv0)
                DOT8(p1, mv1, iv1)
            }
            if (s < G) {
                const h8_t mv0 = *(const h8_t*)&sMeH[idx0 + 8 * s];
                const h8_t iv0 = *(const h8_t*)&sIhR[iofs + 8 * s];
                DOT8(p0, mv0, iv0)
            }
            float p = p0 + p1;
            if (w == 0) {
                // tail fixup: tau = 64c - d, d = 1..f (raw, scaled at merge)
#pragma unroll
                for (int d = 1; d <= 7; ++d) {
                    const float ih = (float)sIhR[8 + 64 * c - d];   // row 0
                    if (d <= f) p = fmaf(mf[d - 1], ih, p);
                }
            }
            if (w < 4) PA[(c + 1) & 1][L][w] = p;
            else       PB[(c + 1) & 1][L][w - 4] = p;
        }
        __syncthreads();
    }
#undef STEPB
#undef STEP_GE1
#undef STEP_GE2
}

// ---------------------------------------------------------------------------
// Launcher: me_kernel (2 blocks) then scan_kernel (256 blocks x 512 threads).
// d_ws layout: [0,4096) fp32 me; [4096,6144) fp16 me.
// ---------------------------------------------------------------------------
extern "C" void kernel_launch(void* const* d_in, const int* in_sizes, int n_in,
                              void* d_out, int out_size, void* d_ws, size_t ws_size,
                              hipStream_t stream) {
    const float* t     = (const float*)d_in[0];
    const float* y     = (const float*)d_in[1];
    const float* w1    = (const float*)d_in[2];
    const float* b1    = (const float*)d_in[3];
    const float* w2    = (const float*)d_in[4];
    const float* b2    = (const float*)d_in[5];
    const float* w3    = (const float*)d_in[6];
    const float* b3    = (const float*)d_in[7];
    const float* w4    = (const float*)d_in[8];
    const float* b4    = (const float*)d_in[9];
    const float* beta  = (const float*)d_in[10];
    const float* gamma = (const float*)d_in[11];

    float*    me_f = (float*)d_ws;
    _Float16* me_h = (_Float16*)((char*)d_ws + 4096);

    me_kernel<<<2, 512, 0, stream>>>(t, w1, b1, w2, b2, w3, b3, w4, b4, me_f, me_h);
    scan_kernel<<<B_N, 512, 0, stream>>>(me_f, me_h, t, y, beta, gamma, (float*)d_out);
}